// Round 1
// baseline (7949.861 us; speedup 1.0000x reference)
//
#include <hip/hip_runtime.h>
#include <hip/hip_fp16.h>
#include <cstdint>
#include <cstddef>

#define B_ 128
#define T_ 2048
#define C_ 16
#define CO_ 128
#define H_ 128
#define G_ 512

typedef _Float16 h2v __attribute__((ext_vector_type(2)));

__device__ __forceinline__ float dot2f(unsigned int a, unsigned int b, float c) {
#if __has_builtin(__builtin_amdgcn_fdot2)
    return __builtin_amdgcn_fdot2(__builtin_bit_cast(h2v, a),
                                  __builtin_bit_cast(h2v, b), c, false);
#else
    __half2 ah = __builtin_bit_cast(__half2, a);
    __half2 bh = __builtin_bit_cast(__half2, b);
    return c + __half2float(ah.x) * __half2float(bh.x)
             + __half2float(ah.y) * __half2float(bh.y);
#endif
}

__device__ __forceinline__ unsigned int packh2(float lo, float hi) {
    __half2 h;
    h.x = __float2half(lo);
    h.y = __float2half(hi);
    return __builtin_bit_cast(unsigned int, h);
}

__device__ __forceinline__ float sigm(float x) { return 1.0f / (1.0f + __expf(-x)); }
__device__ __forceinline__ float tanh_(float x) { return 2.0f / (1.0f + __expf(-2.0f * x)) - 1.0f; }

// 128-element dot product: W[16] uint4 (packed f16 pairs) vs hp[16] uint4 in LDS.
__device__ __forceinline__ float matvec16(const uint4* W, const uint4* hp, float base) {
    float a0 = base, a1 = 0.f, a2 = 0.f, a3 = 0.f;
#pragma unroll
    for (int k = 0; k < 16; ++k) {
        uint4 hv = hp[k];
        a0 = dot2f(W[k].x, hv.x, a0);
        a1 = dot2f(W[k].y, hv.y, a1);
        a2 = dot2f(W[k].z, hv.z, a2);
        a3 = dot2f(W[k].w, hv.w, a3);
    }
    return (a0 + a1) + (a2 + a3);
}

// ---------------------------------------------------------------------------
// Kernel 0: pack 4 weight matrices [512][128] fp32 -> f16 pairs, layout [k4][g]
// m: 0=w_hh0, 1=w_ih1, 2=w_hh1 (into Wpk), 3=w_ih0 (into W0pk)
// ---------------------------------------------------------------------------
__global__ __launch_bounds__(256) void pack_kernel(
    const float* __restrict__ w_ih0, const float* __restrict__ w_hh0,
    const float* __restrict__ w_ih1, const float* __restrict__ w_hh1,
    uint4* __restrict__ Wpk, uint4* __restrict__ W0pk) {
    int tid = blockIdx.x * 256 + threadIdx.x;
    if (tid >= 4 * 8192) return;
    int m  = tid >> 13;
    int r  = tid & 8191;
    int g  = r & 511;
    int k4 = r >> 9;  // 0..15
    const float* src = (m == 0) ? w_hh0 : (m == 1) ? w_ih1 : (m == 2) ? w_hh1 : w_ih0;
    const float* p = src + g * 128 + k4 * 8;
    uint4 o;
    o.x = packh2(p[0], p[1]);
    o.y = packh2(p[2], p[3]);
    o.z = packh2(p[4], p[5]);
    o.w = packh2(p[6], p[7]);
    uint4* dst = (m < 3) ? (Wpk + m * 8192) : W0pk;
    dst[k4 * 512 + g] = o;
}

// ---------------------------------------------------------------------------
// Kernel 1: fused conv1d(k=3,pad=1) + bias + LeakyReLU + w_ih0 projection + bias0
// Writes x0buf[t_local][b][512] fp32 for a 32-row time tile.
// grid: (ct/32, B), block: 512
// ---------------------------------------------------------------------------
__global__ __launch_bounds__(512) void conv_proj_kernel(
    const float* __restrict__ x, const float* __restrict__ conv_w,
    const float* __restrict__ conv_b, const float* __restrict__ b_ih0,
    const float* __restrict__ b_hh0, const uint4* __restrict__ W0pk,
    float* __restrict__ x0buf, int t0) {
    int b   = blockIdx.y;
    int tt  = blockIdx.x;
    int tid = threadIdx.x;
    int t0c = t0 + tt * 32;

    __shared__ float xs[34 * 16];        // x rows t0c-1 .. t0c+32
    __shared__ float cwS[128 * 49];      // conv weights, padded stride 49
    __shared__ float cbS[128];
    __shared__ float b0S[512];
    __shared__ uint4 yS4[32 * 16];       // 32 rows x 128 f16 y values
    __half* yh = (__half*)yS4;

    // per-thread w_ih0 row (g = tid) in registers
    uint4 W0[16];
#pragma unroll
    for (int k = 0; k < 16; ++k) W0[k] = W0pk[k * 512 + tid];

    // stage x (zero-padded at sequence edges)
    for (int idx = tid; idx < 544; idx += 512) {
        int row = idx >> 4, c = idx & 15;
        int gt = t0c - 1 + row;
        xs[idx] = (gt >= 0 && gt < T_) ? x[((size_t)b * T_ + gt) * C_ + c] : 0.f;
    }
    // stage conv weights with +1 pad
    for (int idx = tid; idx < 6144; idx += 512)
        cwS[(idx / 48) * 49 + (idx % 48)] = conv_w[idx];
    if (tid < 128) cbS[tid] = conv_b[tid];
    b0S[tid] = b_ih0[tid] + b_hh0[tid];
    __syncthreads();

    // phase 1: conv + leaky -> yS (f16)
#pragma unroll
    for (int p = 0; p < 8; ++p) {
        int r  = p * 4 + (tid >> 7);
        int co = tid & 127;
        float acc = cbS[co];
        const float* cw = &cwS[co * 49];
#pragma unroll
        for (int i = 0; i < 48; ++i) {
            int c = i / 3, k = i % 3;
            acc += xs[(r + k) * 16 + c] * cw[i];
        }
        acc = acc >= 0.f ? acc : 0.01f * acc;
        yh[r * 128 + co] = __float2half(acc);
    }
    __syncthreads();

    // phase 2: x0[t][b][g] = b0[g] + dot(w_ih0[g,:], y[t,:])
#pragma unroll 2
    for (int r = 0; r < 32; ++r) {
        float acc = matvec16(W0, &yS4[r * 16], b0S[tid]);
        int tl = tt * 32 + r;
        x0buf[((size_t)tl * B_ + b) * G_ + tid] = acc;
    }
}

// ---------------------------------------------------------------------------
// Kernel 2: recurrence. One block per batch element, 512 threads (thread = gate g).
// Weights (3 matrices x 128 f16) live in registers. h vectors broadcast via LDS.
// state: [h0][c0][h1][c1][pooled], each [B][H] fp32.
// ---------------------------------------------------------------------------
__global__ __launch_bounds__(512, 2) void recur_kernel(
    const uint4* __restrict__ Wpk, const float* __restrict__ x0buf,
    const float* __restrict__ b_ih1, const float* __restrict__ b_hh1,
    float* __restrict__ state, int ct) {
    int b = blockIdx.x;
    int g = threadIdx.x;

    __shared__ float g0[G_];
    __shared__ float g1[G_];
    __shared__ uint4 h0p4[16];
    __shared__ uint4 h1p4[16];
    __half* h0h = (__half*)h0p4;
    __half* h1h = (__half*)h1p4;

    uint4 Whh0[16], Wih1[16], Whh1[16];
#pragma unroll
    for (int k = 0; k < 16; ++k) {
        Whh0[k] = Wpk[k * 512 + g];
        Wih1[k] = Wpk[8192 + k * 512 + g];
        Whh1[k] = Wpk[16384 + k * 512 + g];
    }
    float b1g = b_ih1[g] + b_hh1[g];

    float* h0s = state;
    float* c0s = state + B_ * H_;
    float* h1s = state + 2 * B_ * H_;
    float* c1s = state + 3 * B_ * H_;
    float* pooled = state + 4 * B_ * H_;

    float c0 = 0.f, c1 = 0.f, pacc = 0.f;
    if (g < H_) {
        c0 = c0s[b * H_ + g];
        h0h[g] = __float2half(h0s[b * H_ + g]);
    } else if (g < 2 * H_) {
        int j = g - H_;
        c1 = c1s[b * H_ + j];
        h1h[j] = __float2half(h1s[b * H_ + j]);
    }
    __syncthreads();

    const float* xrow = x0buf + (size_t)b * G_ + g;
    float xv = xrow[0];

#pragma unroll 1
    for (int t = 0; t < ct; ++t) {
        // prefetch next step's x0 element (hides HBM latency across the step)
        float xnext = (t + 1 < ct) ? xrow[(size_t)(t + 1) * B_ * G_] : 0.f;

        // layer-1 partial: b1 + w_hh1 . h1(t-1)   (independent of cell0)
        float acc1 = matvec16(Whh1, h1p4, b1g);

        // layer-0 gates: x0 + w_hh0 . h0(t-1)
        float acc0 = matvec16(Whh0, h0p4, xv);
        g0[g] = acc0;
        __syncthreads();

        if (g < H_) {  // cell 0 (waves 0-1)
            float gi = g0[g], gf = g0[g + H_], gg = g0[g + 2 * H_], go = g0[g + 3 * H_];
            c0 = sigm(gf) * c0 + sigm(gi) * tanh_(gg);
            float h0 = sigm(go) * tanh_(c0);
            h0h[g] = __float2half(h0);
        }
        __syncthreads();

        // layer-1 gates: += w_ih1 . h0(t)
        acc1 = matvec16(Wih1, h0p4, acc1);
        g1[g] = acc1;
        xv = xnext;
        __syncthreads();

        if (g >= H_ && g < 2 * H_) {  // cell 1 (waves 2-3)
            int j = g - H_;
            float gi = g1[j], gf = g1[j + H_], gg = g1[j + 2 * H_], go = g1[j + 3 * H_];
            c1 = sigm(gf) * c1 + sigm(gi) * tanh_(gg);
            float h1 = sigm(go) * tanh_(c1);
            h1h[j] = __float2half(h1);
            pacc += h1;
        }
        __syncthreads();
    }

    if (g < H_) {
        c0s[b * H_ + g] = c0;
        h0s[b * H_ + g] = __half2float(h0h[g]);
    } else if (g < 2 * H_) {
        int j = g - H_;
        c1s[b * H_ + j] = c1;
        h1s[b * H_ + j] = __half2float(h1h[j]);
        pooled[b * H_ + j] += pacc;
    }
}

// ---------------------------------------------------------------------------
// Kernel 3: out[b] = mean_t(h1)[b,:] . lin_w + lin_b
// ---------------------------------------------------------------------------
__global__ __launch_bounds__(128) void final_kernel(
    const float* __restrict__ pooled, const float* __restrict__ lin_w,
    const float* __restrict__ lin_b, float* __restrict__ out) {
    int b = blockIdx.x;
    int j = threadIdx.x;
    __shared__ float red[128];
    red[j] = pooled[b * H_ + j] * lin_w[j];
    __syncthreads();
    for (int s = 64; s > 0; s >>= 1) {
        if (j < s) red[j] += red[j + s];
        __syncthreads();
    }
    if (j == 0) out[b] = red[0] * (1.0f / (float)T_) + lin_b[0];
}

// ---------------------------------------------------------------------------
extern "C" void kernel_launch(void* const* d_in, const int* in_sizes, int n_in,
                              void* d_out, int out_size, void* d_ws, size_t ws_size,
                              hipStream_t stream) {
    (void)in_sizes; (void)n_in; (void)out_size;
    const float* x      = (const float*)d_in[0];
    const float* conv_w = (const float*)d_in[1];
    const float* conv_b = (const float*)d_in[2];
    const float* w_ih0  = (const float*)d_in[3];
    const float* w_hh0  = (const float*)d_in[4];
    const float* b_ih0  = (const float*)d_in[5];
    const float* b_hh0  = (const float*)d_in[6];
    const float* w_ih1  = (const float*)d_in[7];
    const float* w_hh1  = (const float*)d_in[8];
    const float* b_ih1  = (const float*)d_in[9];
    const float* b_hh1  = (const float*)d_in[10];
    const float* lin_w  = (const float*)d_in[11];
    const float* lin_b  = (const float*)d_in[12];

    char* ws = (char*)d_ws;
    size_t off = 0;
    float* state = (float*)(ws + off);           // h0,c0,h1,c1,pooled
    off += (size_t)5 * B_ * H_ * sizeof(float);  // 327680, 16B aligned
    uint4* Wpk = (uint4*)(ws + off);
    off += (size_t)3 * 8192 * sizeof(uint4);     // 393216
    uint4* W0pk = (uint4*)(ws + off);
    off += (size_t)8192 * sizeof(uint4);         // 131072
    float* x0buf = (float*)(ws + off);

    size_t perT = (size_t)B_ * G_ * sizeof(float);  // 262144 B per time step
    size_t avail = (ws_size > off) ? (ws_size - off) : 0;
    int chunkT = (int)((avail / perT) / 32) * 32;
    if (chunkT > T_) chunkT = T_;
    if (chunkT < 32) chunkT = 32;  // best effort if ws is tiny

    hipMemsetAsync(state, 0, (size_t)5 * B_ * H_ * sizeof(float), stream);
    pack_kernel<<<(4 * 8192 + 255) / 256, 256, 0, stream>>>(
        w_ih0, w_hh0, w_ih1, w_hh1, Wpk, W0pk);

    for (int t0 = 0; t0 < T_; t0 += chunkT) {
        int ct = T_ - t0;
        if (ct > chunkT) ct = chunkT;
        conv_proj_kernel<<<dim3(ct / 32, B_), 512, 0, stream>>>(
            x, conv_w, conv_b, b_ih0, b_hh0, W0pk, x0buf, t0);
        recur_kernel<<<B_, 512, 0, stream>>>(Wpk, x0buf, b_ih1, b_hh1, state, ct);
    }

    final_kernel<<<B_, 128, 0, stream>>>(state + 4 * B_ * H_, lin_w, lin_b,
                                         (float*)d_out);
}

// Round 2
// 4836.069 us; speedup vs baseline: 1.6439x; 1.6439x over previous
//
#include <hip/hip_runtime.h>
#include <hip/hip_fp16.h>
#include <cstdint>
#include <cstddef>

#define B_ 128
#define T_ 2048
#define C_ 16
#define CO_ 128
#define H_ 128
#define G_ 512

typedef _Float16 half8 __attribute__((ext_vector_type(8)));
typedef float f32x4 __attribute__((ext_vector_type(4)));

__device__ __forceinline__ unsigned packh2f(float a, float b) {
  union { _Float16 h[2]; unsigned u; } x;
  x.h[0] = (_Float16)a; x.h[1] = (_Float16)b;
  return x.u;
}

__device__ __forceinline__ float rcpf(float x) { return __builtin_amdgcn_rcpf(x); }

// ---------------------------------------------------------------------------
// pack_kernel: build MFMA fragment-ordered weight buffers.
//  Wf0  : w_hh0 A-frags, [w][tl][s(0..3)][lane] uint4 (8 f16), spread tiles tau=w+8*tl
//  W1f  : [w_ih1|w_hh1] A-frags, K=256, [w][tl][s(0..7)][lane]
//  WB0f : w_ih0 B-frags for conv proj, [ntile(0..31)][s(0..3)][lane]
//  b1f  : b_ih1+b_hh1 in D-frag order, [w][lane][2 uint4] (halfs [tl*4+reg])
// ---------------------------------------------------------------------------
__global__ __launch_bounds__(256) void pack_kernel(
    const float* __restrict__ w_ih0, const float* __restrict__ w_hh0,
    const float* __restrict__ w_ih1, const float* __restrict__ w_hh1,
    const float* __restrict__ b_ih1, const float* __restrict__ b_hh1,
    uint4* __restrict__ Wf0, uint4* __restrict__ W1f,
    uint4* __restrict__ WB0f, uint4* __restrict__ b1f) {
  int tid = blockIdx.x * 256 + threadIdx.x;
  if (tid < 8192) {
    int u = tid, L = u & 63, s = (u >> 6) & 3, tl = (u >> 8) & 3, w = u >> 10;
    int m = (w + 8 * tl) * 16 + (L & 15);
    int k0 = s * 32 + (L >> 4) * 8;
    const float* p = w_hh0 + m * 128 + k0;
    uint4 o;
    o.x = packh2f(p[0], p[1]); o.y = packh2f(p[2], p[3]);
    o.z = packh2f(p[4], p[5]); o.w = packh2f(p[6], p[7]);
    Wf0[u] = o;
  } else if (tid < 24576) {
    int u = tid - 8192, L = u & 63, s = (u >> 6) & 7, tl = (u >> 9) & 3, w = u >> 11;
    int m = (w + 8 * tl) * 16 + (L & 15);
    int k0 = s * 32 + (L >> 4) * 8;
    float v[8];
#pragma unroll
    for (int e = 0; e < 8; ++e) {
      int k = k0 + e;
      v[e] = (k < 128) ? w_ih1[m * 128 + k] : w_hh1[m * 128 + k - 128];
    }
    uint4 o;
    o.x = packh2f(v[0], v[1]); o.y = packh2f(v[2], v[3]);
    o.z = packh2f(v[4], v[5]); o.w = packh2f(v[6], v[7]);
    W1f[u] = o;
  } else if (tid < 32768) {
    int u = tid - 24576, L = u & 63, s = (u >> 6) & 3, nt = u >> 8;
    int g = nt * 16 + (L & 15);
    int k0 = s * 32 + (L >> 4) * 8;
    const float* p = w_ih0 + g * 128 + k0;
    uint4 o;
    o.x = packh2f(p[0], p[1]); o.y = packh2f(p[2], p[3]);
    o.z = packh2f(p[4], p[5]); o.w = packh2f(p[6], p[7]);
    WB0f[u] = o;
  } else if (tid < 33792) {
    int u = tid - 32768;
    int h = u & 1, slot = u >> 1, L = slot & 63, w = slot >> 6, q = L >> 4;
    float v[8];
#pragma unroll
    for (int e = 0; e < 8; ++e) {
      int j = h * 8 + e, tl = j >> 2, reg = j & 3;
      int row = (w + 8 * tl) * 16 + q * 4 + reg;
      v[e] = b_ih1[row] + b_hh1[row];
    }
    uint4 o;
    o.x = packh2f(v[0], v[1]); o.y = packh2f(v[2], v[3]);
    o.z = packh2f(v[4], v[5]); o.w = packh2f(v[6], v[7]);
    b1f[u] = o;
  }
}

// ---------------------------------------------------------------------------
// conv_proj: conv1d(k=3,pad=1)+bias+LeakyReLU -> y f16; then x0 = y @ w_ih0^T + b0
// via MFMA. Output written in recur's per-lane fragment layout:
//   x0f halfs: [t_local][b16][w2][lane(n2+16*q2)][16 halfs: tl2*4+reg2]
// grid (ct/32, 128), block 512.
// ---------------------------------------------------------------------------
__global__ __launch_bounds__(512, 2) void conv_proj_kernel(
    const float* __restrict__ x, const float* __restrict__ conv_w,
    const float* __restrict__ conv_b, const float* __restrict__ b_ih0,
    const float* __restrict__ b_hh0, const uint4* __restrict__ WB0f,
    uint4* __restrict__ x0f, int t0) {
  int b = blockIdx.y;
  int tt = blockIdx.x;
  int tid = threadIdx.x;
  int w = tid >> 6, L = tid & 63, q = L >> 4, n = L & 15;
  int t0c = t0 + tt * 32;

  __shared__ float xs[34 * 16];
  __shared__ __align__(16) _Float16 yh[32 * 136];   // conv out, padded stride
  __shared__ __align__(16) _Float16 x0S[32 * 512];  // frag-ordered x0 staging

  // conv weights for this thread's output channel, in registers
  int co = tid & 127;
  float cw[48];
#pragma unroll
  for (int i = 0; i < 12; ++i) {
    const float4 v = *(const float4*)(conv_w + co * 48 + i * 4);
    cw[i * 4 + 0] = v.x; cw[i * 4 + 1] = v.y;
    cw[i * 4 + 2] = v.z; cw[i * 4 + 3] = v.w;
  }
  float cb = conv_b[co];

  // w_ih0 B-frags in registers (this wave's 4 gate tiles)
  half8 WB[4][4];
#pragma unroll
  for (int nt4 = 0; nt4 < 4; ++nt4)
#pragma unroll
    for (int s = 0; s < 4; ++s)
      WB[nt4][s] = __builtin_bit_cast(half8, WB0f[((w * 4 + nt4) * 4 + s) * 64 + L]);
  float b0v[4];
#pragma unroll
  for (int nt4 = 0; nt4 < 4; ++nt4) {
    int g = (w * 4 + nt4) * 16 + n;
    b0v[nt4] = b_ih0[g] + b_hh0[g];
  }

  // stage x rows t0c-1 .. t0c+32
  for (int idx = tid; idx < 544; idx += 512) {
    int row = idx >> 4, c = idx & 15;
    int gt = t0c - 1 + row;
    xs[idx] = (gt >= 0 && gt < T_) ? x[((size_t)b * T_ + gt) * C_ + c] : 0.f;
  }
  __syncthreads();

  // conv + leaky -> yh f16
#pragma unroll
  for (int p = 0; p < 8; ++p) {
    int r = p * 4 + (tid >> 7);
    float acc = cb;
#pragma unroll
    for (int c16 = 0; c16 < 16; ++c16)
#pragma unroll
      for (int k = 0; k < 3; ++k)
        acc += xs[(r + k) * 16 + c16] * cw[c16 * 3 + k];
    acc = acc >= 0.f ? acc : 0.01f * acc;
    yh[r * 136 + co] = (_Float16)acc;
  }
  __syncthreads();

  // MFMA projection: M=t-rows(32), N=gates(512), K=128
#pragma unroll
  for (int mt = 0; mt < 2; ++mt) {
    half8 A[4];
#pragma unroll
    for (int s = 0; s < 4; ++s)
      A[s] = *(const half8*)&yh[(mt * 16 + n) * 136 + s * 32 + q * 8];
#pragma unroll
    for (int nt4 = 0; nt4 < 4; ++nt4) {
      f32x4 acc = {b0v[nt4], b0v[nt4], b0v[nt4], b0v[nt4]};
#pragma unroll
      for (int s = 0; s < 4; ++s)
        acc = __builtin_amdgcn_mfma_f32_16x16x32_f16(A[s], WB[nt4][s], acc, 0, 0, 0);
      // D: row(t) = mt*16 + q*4 + reg, col(gate-in-tile) = n; tile tau = w*4+nt4
      int tau = w * 4 + nt4;
      int off = (tau & 7) * 64 + (n >> 2) * 16 + (tau >> 3) * 4 + (n & 3);
#pragma unroll
      for (int reg = 0; reg < 4; ++reg)
        x0S[(mt * 16 + q * 4 + reg) * 512 + off] = (_Float16)acc[reg];
    }
  }
  __syncthreads();

  // coalesced write-out: 1024 chunks of 32B
  int n2 = b & 15, b16 = b >> 4;
#pragma unroll
  for (int k = 0; k < 2; ++k) {
    int c = k * 512 + tid;
    int r = c >> 5, wq = c & 31;
    int w2 = wq >> 2, q2 = wq & 3;
    const uint4* src = (const uint4*)&x0S[r * 512 + wq * 16];
    size_t gidx = ((((size_t)(tt * 32 + r) * 8 + b16) * 8 + w2) * 64 + (n2 + 16 * q2)) * 2;
    x0f[gidx] = src[0];
    x0f[gidx + 1] = src[1];
  }
}

// ---------------------------------------------------------------------------
// recur_kernel: 8 blocks x 512 threads; block = 16 batch elements.
// Weights as A-frags in registers; h via double-buffered LDS B-frags;
// one __syncthreads per step.
// ---------------------------------------------------------------------------
__global__ __launch_bounds__(512, 2) void recur_kernel(
    const uint4* __restrict__ Wf0, const uint4* __restrict__ W1f,
    const uint4* __restrict__ b1f, const uint4* __restrict__ x0f,
    f32x4* __restrict__ csave, uint2* __restrict__ hsave,
    f32x4* __restrict__ psave, int ct) {
  int b16 = blockIdx.x;
  int tid = threadIdx.x;
  int w = tid >> 6, L = tid & 63, q = L >> 4, n = L & 15;

  // h buffers: [0]=h0 par0, [1]=h0 par1, [2]=h1 par0, [3]=h1 par1
  __shared__ __align__(16) _Float16 hb[4][16 * 136];

  // weights -> registers
  half8 WA0[4][4];
#pragma unroll
  for (int tl = 0; tl < 4; ++tl)
#pragma unroll
    for (int s = 0; s < 4; ++s)
      WA0[tl][s] = __builtin_bit_cast(half8, Wf0[((w * 4 + tl) * 4 + s) * 64 + L]);
  half8 WA1[4][8];
#pragma unroll
  for (int tl = 0; tl < 4; ++tl)
#pragma unroll
    for (int s = 0; s < 8; ++s)
      WA1[tl][s] = __builtin_bit_cast(half8, W1f[((w * 4 + tl) * 8 + s) * 64 + L]);
  half8 b1lo = __builtin_bit_cast(half8, b1f[(w * 64 + L) * 2]);
  half8 b1hi = __builtin_bit_cast(half8, b1f[(w * 64 + L) * 2 + 1]);

  int sid = (b16 * 8 + w) * 64 + L;
  f32x4 c0v = csave[sid];
  f32x4 c1v = csave[4096 + sid];
  f32x4 pool = psave[sid];
  uint2 h0p = hsave[sid];
  uint2 h1p = hsave[4096 + sid];

  int hoff = n * 136 + w * 16 + q * 4;  // halfs
  *(uint2*)&hb[1][hoff] = h0p;          // state as-if written at step -1 (parity 1)
  *(uint2*)&hb[3][hoff] = h1p;
  __syncthreads();

  const uint4* xp = x0f + (((size_t)b16 * 8 + w) * 64 + L) * 2;
  const size_t tstride = 8192;  // uint4 per time step
  uint4 pf0 = xp[0];
  uint4 pf1 = xp[1];

#pragma unroll 1
  for (int i = 0; i < ct; ++i) {
    int c = i & 1, p = c ^ 1;

    // ---- phase A: gates0 = x0 + Whh0 . h0(t-1) ----
    f32x4 acc[4];
    {
      half8 xlo = __builtin_bit_cast(half8, pf0);
      half8 xhi = __builtin_bit_cast(half8, pf1);
      acc[0] = (f32x4){(float)xlo[0], (float)xlo[1], (float)xlo[2], (float)xlo[3]};
      acc[1] = (f32x4){(float)xlo[4], (float)xlo[5], (float)xlo[6], (float)xlo[7]};
      acc[2] = (f32x4){(float)xhi[0], (float)xhi[1], (float)xhi[2], (float)xhi[3]};
      acc[3] = (f32x4){(float)xhi[4], (float)xhi[5], (float)xhi[6], (float)xhi[7]};
    }
    half8 B0[4];
#pragma unroll
    for (int s = 0; s < 4; ++s)
      B0[s] = *(const half8*)&hb[p][n * 136 + s * 32 + q * 8];
#pragma unroll
    for (int s = 0; s < 4; ++s)
#pragma unroll
      for (int tl = 0; tl < 4; ++tl)
        acc[tl] = __builtin_amdgcn_mfma_f32_16x16x32_f16(WA0[tl][s], B0[s], acc[tl], 0, 0, 0);

    // prefetch next step's x0 fragment (consumed at i+1)
    {
      int tn = i + 1 < ct ? i + 1 : ct - 1;
      pf0 = xp[(size_t)tn * tstride];
      pf1 = xp[(size_t)tn * tstride + 1];
    }

    // ---- cell 0 (per-lane: i,f,g,o for j = w*16+q*4+reg, batch n) ----
    float h0v[4];
#pragma unroll
    for (int r2 = 0; r2 < 4; ++r2) {
      float iv = acc[0][r2], fv = acc[1][r2], gv = acc[2][r2], ov = acc[3][r2];
      gv = fminf(fmaxf(gv, -15.f), 15.f);
      float ei = __expf(-iv), ef = __expf(-fv), eg = __expf(2.f * gv);
      float sf = rcpf(1.f + ef);
      float itg = (eg - 1.f) * rcpf((1.f + ei) * (eg + 1.f));
      float cN = sf * c0v[r2] + itg;
      c0v[r2] = cN;
      float cc = fminf(fmaxf(cN, -15.f), 15.f);
      float eo = __expf(-ov), ec = __expf(2.f * cc);
      h0v[r2] = (ec - 1.f) * rcpf((1.f + eo) * (ec + 1.f));
    }
    h0p.x = packh2f(h0v[0], h0v[1]);
    h0p.y = packh2f(h0v[2], h0v[3]);
    *(uint2*)&hb[c][hoff] = h0p;
    __syncthreads();

    // ---- phase B: gates1 = b1 + Wih1 . h0(t) + Whh1 . h1(t-1) ----
    acc[0] = (f32x4){(float)b1lo[0], (float)b1lo[1], (float)b1lo[2], (float)b1lo[3]};
    acc[1] = (f32x4){(float)b1lo[4], (float)b1lo[5], (float)b1lo[6], (float)b1lo[7]};
    acc[2] = (f32x4){(float)b1hi[0], (float)b1hi[1], (float)b1hi[2], (float)b1hi[3]};
    acc[3] = (f32x4){(float)b1hi[4], (float)b1hi[5], (float)b1hi[6], (float)b1hi[7]};
    half8 B1[8];
#pragma unroll
    for (int s = 0; s < 4; ++s)
      B1[s] = *(const half8*)&hb[c][n * 136 + s * 32 + q * 8];
#pragma unroll
    for (int s = 4; s < 8; ++s)
      B1[s] = *(const half8*)&hb[2 + p][n * 136 + (s - 4) * 32 + q * 8];
#pragma unroll
    for (int s = 0; s < 8; ++s)
#pragma unroll
      for (int tl = 0; tl < 4; ++tl)
        acc[tl] = __builtin_amdgcn_mfma_f32_16x16x32_f16(WA1[tl][s], B1[s], acc[tl], 0, 0, 0);

    // ---- cell 1 ----
    float h1v[4];
#pragma unroll
    for (int r2 = 0; r2 < 4; ++r2) {
      float iv = acc[0][r2], fv = acc[1][r2], gv = acc[2][r2], ov = acc[3][r2];
      gv = fminf(fmaxf(gv, -15.f), 15.f);
      float ei = __expf(-iv), ef = __expf(-fv), eg = __expf(2.f * gv);
      float sf = rcpf(1.f + ef);
      float itg = (eg - 1.f) * rcpf((1.f + ei) * (eg + 1.f));
      float cN = sf * c1v[r2] + itg;
      c1v[r2] = cN;
      float cc = fminf(fmaxf(cN, -15.f), 15.f);
      float eo = __expf(-ov), ec = __expf(2.f * cc);
      h1v[r2] = (ec - 1.f) * rcpf((1.f + eo) * (ec + 1.f));
      pool[r2] += h1v[r2];
    }
    h1p.x = packh2f(h1v[0], h1v[1]);
    h1p.y = packh2f(h1v[2], h1v[3]);
    *(uint2*)&hb[2 + c][hoff] = h1p;
    // no second barrier needed: next touch of hb[2+c] readers is after next
    // step's barrier; next writer is two steps away (verified hazard analysis)
  }

  csave[sid] = c0v;
  csave[4096 + sid] = c1v;
  psave[sid] = pool;
  hsave[sid] = h0p;
  hsave[4096 + sid] = h1p;
}

// ---------------------------------------------------------------------------
// final: out[b] = (sum_j pooled[j,b] * lin_w[j]) / T + lin_b
// ---------------------------------------------------------------------------
__global__ __launch_bounds__(128) void final_kernel(
    const f32x4* __restrict__ psave, const float* __restrict__ lin_w,
    const float* __restrict__ lin_b, float* __restrict__ out) {
  int b = threadIdx.x;
  int n = b & 15, b16 = b >> 4;
  float acc = 0.f;
  for (int w = 0; w < 8; ++w)
#pragma unroll
    for (int q = 0; q < 4; ++q) {
      f32x4 v = psave[(b16 * 8 + w) * 64 + n + 16 * q];
#pragma unroll
      for (int reg = 0; reg < 4; ++reg)
        acc += v[reg] * lin_w[w * 16 + q * 4 + reg];
    }
  out[b] = acc * (1.0f / (float)T_) + lin_b[0];
}

// ---------------------------------------------------------------------------
extern "C" void kernel_launch(void* const* d_in, const int* in_sizes, int n_in,
                              void* d_out, int out_size, void* d_ws, size_t ws_size,
                              hipStream_t stream) {
  (void)in_sizes; (void)n_in; (void)out_size;
  const float* x      = (const float*)d_in[0];
  const float* conv_w = (const float*)d_in[1];
  const float* conv_b = (const float*)d_in[2];
  const float* w_ih0  = (const float*)d_in[3];
  const float* w_hh0  = (const float*)d_in[4];
  const float* b_ih0  = (const float*)d_in[5];
  const float* b_hh0  = (const float*)d_in[6];
  const float* w_ih1  = (const float*)d_in[7];
  const float* w_hh1  = (const float*)d_in[8];
  const float* b_ih1  = (const float*)d_in[9];
  const float* b_hh1  = (const float*)d_in[10];
  const float* lin_w  = (const float*)d_in[11];
  const float* lin_b  = (const float*)d_in[12];

  char* ws = (char*)d_ws;
  uint4* Wf0   = (uint4*)(ws + 0);        // 131072 B
  uint4* W1f   = (uint4*)(ws + 131072);   // 262144 B
  uint4* WB0f  = (uint4*)(ws + 393216);   // 131072 B
  uint4* b1f   = (uint4*)(ws + 524288);   // 16384 B
  f32x4* csave = (f32x4*)(ws + 540672);   // 131072 B (c0|c1)
  uint2* hsave = (uint2*)(ws + 671744);   // 65536 B (h0|h1)
  f32x4* psave = (f32x4*)(ws + 737280);   // 65536 B
  uint4* x0f   = (uint4*)(ws + 802816);   // chunkT * 131072 B

  size_t perT = (size_t)B_ * G_ * 2;  // 131072 B per time step (f16)
  size_t avail = (ws_size > 802816) ? (ws_size - 802816) : 0;
  int chunkT = (int)((avail / perT) / 32) * 32;
  if (chunkT > T_) chunkT = T_;
  if (chunkT < 32) chunkT = 32;

  hipMemsetAsync(ws + 540672, 0, 262144, stream);  // zero c/h/pool state
  pack_kernel<<<132, 256, 0, stream>>>(w_ih0, w_hh0, w_ih1, w_hh1, b_ih1, b_hh1,
                                       Wf0, W1f, WB0f, b1f);

  for (int t0 = 0; t0 < T_; t0 += chunkT) {
    int ct = T_ - t0;
    if (ct > chunkT) ct = chunkT;
    conv_proj_kernel<<<dim3(ct / 32, B_), 512, 0, stream>>>(
        x, conv_w, conv_b, b_ih0, b_hh0, WB0f, x0f, t0);
    recur_kernel<<<8, 512, 0, stream>>>(Wf0, W1f, b1f, x0f,
                                        csave, hsave, psave, ct);
  }

  final_kernel<<<1, 128, 0, stream>>>(psave, lin_w, lin_b, (float*)d_out);
}

// Round 3
// 4058.766 us; speedup vs baseline: 1.9587x; 1.1915x over previous
//
#include <hip/hip_runtime.h>
#include <hip/hip_fp16.h>
#include <cstdint>
#include <cstddef>

#define B_ 128
#define T_ 2048
#define C_ 16
#define CO_ 128
#define H_ 128
#define G_ 512

typedef _Float16 half8 __attribute__((ext_vector_type(8)));
typedef float f32x4 __attribute__((ext_vector_type(4)));

__device__ __forceinline__ unsigned packh2f(float a, float b) {
  union { _Float16 h[2]; unsigned u; } x;
  x.h[0] = (_Float16)a; x.h[1] = (_Float16)b;
  return x.u;
}

__device__ __forceinline__ float rcpf(float x) { return __builtin_amdgcn_rcpf(x); }

// ---------------------------------------------------------------------------
// pack_kernel: fragment-ordered weight buffers.
//  Wf0   : w_hh0 A-frags  [w][tl][s4][L], spread tiles tau = w + 8*tl
//  Wih1f : w_ih1 A-frags  (same layout, K=128)  -- used by proj1
//  Whh1f : w_hh1 A-frags  (same layout, K=128)  -- used by recur1
//  WB0f  : w_ih0 B-frags for conv proj
//  b1fD  : b_ih1+b_hh1 f32 in D-frag per-lane order [w][L][tl(4)][reg(4)]
// ---------------------------------------------------------------------------
__global__ __launch_bounds__(256) void pack_kernel(
    const float* __restrict__ w_ih0, const float* __restrict__ w_hh0,
    const float* __restrict__ w_ih1, const float* __restrict__ w_hh1,
    const float* __restrict__ b_ih1, const float* __restrict__ b_hh1,
    uint4* __restrict__ Wf0, uint4* __restrict__ Wih1f,
    uint4* __restrict__ Whh1f, uint4* __restrict__ WB0f,
    f32x4* __restrict__ b1fD) {
  int tid = blockIdx.x * 256 + threadIdx.x;
  if (tid < 24576) {
    int u = tid & 8191, L = u & 63, s = (u >> 6) & 3, tl = (u >> 8) & 3, w = u >> 10;
    int which = tid >> 13;  // 0=w_hh0, 1=w_ih1, 2=w_hh1
    const float* src = (which == 0) ? w_hh0 : (which == 1) ? w_ih1 : w_hh1;
    uint4* dst = (which == 0) ? Wf0 : (which == 1) ? Wih1f : Whh1f;
    int m = (w + 8 * tl) * 16 + (L & 15);
    int k0 = s * 32 + (L >> 4) * 8;
    const float* p = src + m * 128 + k0;
    uint4 o;
    o.x = packh2f(p[0], p[1]); o.y = packh2f(p[2], p[3]);
    o.z = packh2f(p[4], p[5]); o.w = packh2f(p[6], p[7]);
    dst[u] = o;
  } else if (tid < 32768) {
    int u = tid - 24576, L = u & 63, s = (u >> 6) & 3, nt = u >> 8;
    int g = nt * 16 + (L & 15);
    int k0 = s * 32 + (L >> 4) * 8;
    const float* p = w_ih0 + g * 128 + k0;
    uint4 o;
    o.x = packh2f(p[0], p[1]); o.y = packh2f(p[2], p[3]);
    o.z = packh2f(p[4], p[5]); o.w = packh2f(p[6], p[7]);
    WB0f[u] = o;
  } else if (tid < 34816) {
    int u2 = tid - 32768;            // [w(8)][L(64)][tl(4)]
    int tl = u2 & 3, L = (u2 >> 2) & 63, w = u2 >> 8;
    int q = L >> 4;
    f32x4 o;
#pragma unroll
    for (int reg = 0; reg < 4; ++reg) {
      int row = (w + 8 * tl) * 16 + q * 4 + reg;
      o[reg] = b_ih1[row] + b_hh1[row];
    }
    b1fD[u2] = o;
  }
}

// ---------------------------------------------------------------------------
// conv_proj: conv1d(k=3,pad=1)+bias+LeakyReLU -> y f16; x0 = y @ w_ih0^T + b0
// via MFMA; output f16 in recur0's per-lane fragment layout.
// grid (ct/32, 128), block 512.
// ---------------------------------------------------------------------------
__global__ __launch_bounds__(512, 2) void conv_proj_kernel(
    const float* __restrict__ x, const float* __restrict__ conv_w,
    const float* __restrict__ conv_b, const float* __restrict__ b_ih0,
    const float* __restrict__ b_hh0, const uint4* __restrict__ WB0f,
    uint4* __restrict__ x0f, int t0) {
  int b = blockIdx.y;
  int tt = blockIdx.x;
  int tid = threadIdx.x;
  int w = tid >> 6, L = tid & 63, q = L >> 4, n = L & 15;
  int t0c = t0 + tt * 32;

  __shared__ float xs[34 * 16];
  __shared__ __align__(16) _Float16 yh[32 * 136];
  __shared__ __align__(16) _Float16 x0S[32 * 512];

  int co = tid & 127;
  float cw[48];
#pragma unroll
  for (int i = 0; i < 12; ++i) {
    const float4 v = *(const float4*)(conv_w + co * 48 + i * 4);
    cw[i * 4 + 0] = v.x; cw[i * 4 + 1] = v.y;
    cw[i * 4 + 2] = v.z; cw[i * 4 + 3] = v.w;
  }
  float cb = conv_b[co];

  half8 WB[4][4];
#pragma unroll
  for (int nt4 = 0; nt4 < 4; ++nt4)
#pragma unroll
    for (int s = 0; s < 4; ++s)
      WB[nt4][s] = __builtin_bit_cast(half8, WB0f[((w * 4 + nt4) * 4 + s) * 64 + L]);
  float b0v[4];
#pragma unroll
  for (int nt4 = 0; nt4 < 4; ++nt4) {
    int g = (w * 4 + nt4) * 16 + n;
    b0v[nt4] = b_ih0[g] + b_hh0[g];
  }

  for (int idx = tid; idx < 544; idx += 512) {
    int row = idx >> 4, c = idx & 15;
    int gt = t0c - 1 + row;
    xs[idx] = (gt >= 0 && gt < T_) ? x[((size_t)b * T_ + gt) * C_ + c] : 0.f;
  }
  __syncthreads();

#pragma unroll
  for (int p = 0; p < 8; ++p) {
    int r = p * 4 + (tid >> 7);
    float acc = cb;
#pragma unroll
    for (int c16 = 0; c16 < 16; ++c16)
#pragma unroll
      for (int k = 0; k < 3; ++k)
        acc += xs[(r + k) * 16 + c16] * cw[c16 * 3 + k];
    acc = acc >= 0.f ? acc : 0.01f * acc;
    yh[r * 136 + co] = (_Float16)acc;
  }
  __syncthreads();

#pragma unroll
  for (int mt = 0; mt < 2; ++mt) {
    half8 A[4];
#pragma unroll
    for (int s = 0; s < 4; ++s)
      A[s] = *(const half8*)&yh[(mt * 16 + n) * 136 + s * 32 + q * 8];
#pragma unroll
    for (int nt4 = 0; nt4 < 4; ++nt4) {
      f32x4 acc = {b0v[nt4], b0v[nt4], b0v[nt4], b0v[nt4]};
#pragma unroll
      for (int s = 0; s < 4; ++s)
        acc = __builtin_amdgcn_mfma_f32_16x16x32_f16(A[s], WB[nt4][s], acc, 0, 0, 0);
      int tau = w * 4 + nt4;
      int off = (tau & 7) * 64 + (n >> 2) * 16 + (tau >> 3) * 4 + (n & 3);
#pragma unroll
      for (int reg = 0; reg < 4; ++reg)
        x0S[(mt * 16 + q * 4 + reg) * 512 + off] = (_Float16)acc[reg];
    }
  }
  __syncthreads();

  int n2 = b & 15, b16 = b >> 4;
#pragma unroll
  for (int k = 0; k < 2; ++k) {
    int c = k * 512 + tid;
    int r = c >> 5, wq = c & 31;
    int w2 = wq >> 2, q2 = wq & 3;
    const uint4* src = (const uint4*)&x0S[r * 512 + wq * 16];
    size_t gidx = ((((size_t)(tt * 32 + r) * 8 + b16) * 8 + w2) * 64 + (n2 + 16 * q2)) * 2;
    x0f[gidx] = src[0];
    x0f[gidx + 1] = src[1];
  }
}

// ---------------------------------------------------------------------------
// recur0: layer-0 recurrence only. 8 blocks x 512. Streams h0(t) f16 to h0g:
//   h0g halfs layout: [t][b16][n(16)][j(128)]
// ---------------------------------------------------------------------------
__global__ __launch_bounds__(512, 2) void recur0_kernel(
    const uint4* __restrict__ Wf0, const uint4* __restrict__ x0f,
    f32x4* __restrict__ csave, uint2* __restrict__ hsave,
    uint2* __restrict__ h0g, int ct) {
  int b16 = blockIdx.x;
  int tid = threadIdx.x;
  int w = tid >> 6, L = tid & 63, q = L >> 4, n = L & 15;

  __shared__ __align__(16) _Float16 hb[2][16 * 136];

  half8 WA0[4][4];
#pragma unroll
  for (int tl = 0; tl < 4; ++tl)
#pragma unroll
    for (int s = 0; s < 4; ++s)
      WA0[tl][s] = __builtin_bit_cast(half8, Wf0[((w * 4 + tl) * 4 + s) * 64 + L]);

  int sid = (b16 * 8 + w) * 64 + L;
  f32x4 c0v = csave[sid];
  uint2 h0p = hsave[sid];

  int hoff = n * 136 + w * 16 + q * 4;
  *(uint2*)&hb[1][hoff] = h0p;
  __syncthreads();

  const uint4* xp = x0f + (((size_t)b16 * 8 + w) * 64 + L) * 2;
  uint2* hg = h0g + (b16 * 16 + n) * 32 + w * 4 + q;
  uint4 pf0 = xp[0];
  uint4 pf1 = xp[1];

#pragma unroll 1
  for (int i = 0; i < ct; ++i) {
    int c = i & 1, p = c ^ 1;

    f32x4 acc[4];
    {
      half8 xlo = __builtin_bit_cast(half8, pf0);
      half8 xhi = __builtin_bit_cast(half8, pf1);
      acc[0] = (f32x4){(float)xlo[0], (float)xlo[1], (float)xlo[2], (float)xlo[3]};
      acc[1] = (f32x4){(float)xlo[4], (float)xlo[5], (float)xlo[6], (float)xlo[7]};
      acc[2] = (f32x4){(float)xhi[0], (float)xhi[1], (float)xhi[2], (float)xhi[3]};
      acc[3] = (f32x4){(float)xhi[4], (float)xhi[5], (float)xhi[6], (float)xhi[7]};
    }
    half8 B0[4];
#pragma unroll
    for (int s = 0; s < 4; ++s)
      B0[s] = *(const half8*)&hb[p][n * 136 + s * 32 + q * 8];
#pragma unroll
    for (int s = 0; s < 4; ++s)
#pragma unroll
      for (int tl = 0; tl < 4; ++tl)
        acc[tl] = __builtin_amdgcn_mfma_f32_16x16x32_f16(WA0[tl][s], B0[s], acc[tl], 0, 0, 0);

    {
      int tn = i + 1 < ct ? i + 1 : ct - 1;
      pf0 = xp[(size_t)tn * 8192];
      pf1 = xp[(size_t)tn * 8192 + 1];
    }

    float h0v[4];
#pragma unroll
    for (int r2 = 0; r2 < 4; ++r2) {
      float iv = acc[0][r2], fv = acc[1][r2], gv = acc[2][r2], ov = acc[3][r2];
      gv = fminf(fmaxf(gv, -15.f), 15.f);
      float ei = __expf(-iv), ef = __expf(-fv), eg = __expf(2.f * gv);
      float sf = rcpf(1.f + ef);
      float itg = (eg - 1.f) * rcpf((1.f + ei) * (eg + 1.f));
      float cN = sf * c0v[r2] + itg;
      c0v[r2] = cN;
      float cc = fminf(fmaxf(cN, -15.f), 15.f);
      float eo = __expf(-ov), ec = __expf(2.f * cc);
      h0v[r2] = (ec - 1.f) * rcpf((1.f + eo) * (ec + 1.f));
    }
    h0p.x = packh2f(h0v[0], h0v[1]);
    h0p.y = packh2f(h0v[2], h0v[3]);
    *(uint2*)&hb[c][hoff] = h0p;
    hg[(size_t)i * 4096] = h0p;
    __syncthreads();
  }

  csave[sid] = c0v;
  hsave[sid] = h0p;
}

// ---------------------------------------------------------------------------
// proj1: z1 = Wih1 . h0 + b1 for a chunk (parallel GEMM, no recurrence).
// Output f32 in recur1's per-lane D layout: z1g[((t*8+b16)*8+w)*64+L][tl] f32x4
// grid (ct/8, 8), block 512.
// ---------------------------------------------------------------------------
__global__ __launch_bounds__(512, 2) void proj1_kernel(
    const uint4* __restrict__ Wih1f, const f32x4* __restrict__ b1fD,
    const _Float16* __restrict__ h0gh, f32x4* __restrict__ z1g, int ct) {
  int t8 = blockIdx.x, b16 = blockIdx.y;
  int tid = threadIdx.x;
  int w = tid >> 6, L = tid & 63, q = L >> 4, n = L & 15;

  half8 A1[4][4];
#pragma unroll
  for (int tl = 0; tl < 4; ++tl)
#pragma unroll
    for (int s = 0; s < 4; ++s)
      A1[tl][s] = __builtin_bit_cast(half8, Wih1f[((w * 4 + tl) * 4 + s) * 64 + L]);
  f32x4 bacc[4];
#pragma unroll
  for (int tl = 0; tl < 4; ++tl) bacc[tl] = b1fD[(w * 64 + L) * 4 + tl];

#pragma unroll 1
  for (int tt = 0; tt < 8; ++tt) {
    int t = t8 * 8 + tt;
    const _Float16* hp = h0gh + ((size_t)(t * 8 + b16) * 16 + n) * 128 + q * 8;
    half8 B[4];
#pragma unroll
    for (int s = 0; s < 4; ++s) B[s] = *(const half8*)(hp + s * 32);
    f32x4 acc[4];
#pragma unroll
    for (int tl = 0; tl < 4; ++tl) acc[tl] = bacc[tl];
#pragma unroll
    for (int s = 0; s < 4; ++s)
#pragma unroll
      for (int tl = 0; tl < 4; ++tl)
        acc[tl] = __builtin_amdgcn_mfma_f32_16x16x32_f16(A1[tl][s], B[s], acc[tl], 0, 0, 0);
    f32x4* zp = z1g + (((size_t)(t * 8 + b16) * 8 + w) * 64 + L) * 4;
#pragma unroll
    for (int tl = 0; tl < 4; ++tl) zp[tl] = acc[tl];
  }
}

// ---------------------------------------------------------------------------
// recur1: layer-1 recurrence. 8 blocks x 512. acc init = z1 (f32, no cvt).
// ---------------------------------------------------------------------------
__global__ __launch_bounds__(512, 2) void recur1_kernel(
    const uint4* __restrict__ Whh1f, const f32x4* __restrict__ z1g,
    f32x4* __restrict__ csave, uint2* __restrict__ hsave,
    f32x4* __restrict__ psave, int ct) {
  int b16 = blockIdx.x;
  int tid = threadIdx.x;
  int w = tid >> 6, L = tid & 63, q = L >> 4, n = L & 15;

  __shared__ __align__(16) _Float16 hb[2][16 * 136];

  half8 WA1[4][4];
#pragma unroll
  for (int tl = 0; tl < 4; ++tl)
#pragma unroll
    for (int s = 0; s < 4; ++s)
      WA1[tl][s] = __builtin_bit_cast(half8, Whh1f[((w * 4 + tl) * 4 + s) * 64 + L]);

  int sid = (b16 * 8 + w) * 64 + L;
  f32x4 c1v = csave[4096 + sid];
  uint2 h1p = hsave[4096 + sid];
  f32x4 pool = psave[sid];

  int hoff = n * 136 + w * 16 + q * 4;
  *(uint2*)&hb[1][hoff] = h1p;
  __syncthreads();

  const f32x4* zp = z1g + (((size_t)b16 * 8 + w) * 64 + L) * 4;
  f32x4 pf[4];
#pragma unroll
  for (int tl = 0; tl < 4; ++tl) pf[tl] = zp[tl];

#pragma unroll 1
  for (int i = 0; i < ct; ++i) {
    int c = i & 1, p = c ^ 1;

    f32x4 acc[4];
#pragma unroll
    for (int tl = 0; tl < 4; ++tl) acc[tl] = pf[tl];

    half8 B1[4];
#pragma unroll
    for (int s = 0; s < 4; ++s)
      B1[s] = *(const half8*)&hb[p][n * 136 + s * 32 + q * 8];
#pragma unroll
    for (int s = 0; s < 4; ++s)
#pragma unroll
      for (int tl = 0; tl < 4; ++tl)
        acc[tl] = __builtin_amdgcn_mfma_f32_16x16x32_f16(WA1[tl][s], B1[s], acc[tl], 0, 0, 0);

    {
      size_t tn = (i + 1 < ct) ? (size_t)(i + 1) : (size_t)(ct - 1);
#pragma unroll
      for (int tl = 0; tl < 4; ++tl) pf[tl] = zp[tn * 16384 + tl];
    }

    float h1v[4];
#pragma unroll
    for (int r2 = 0; r2 < 4; ++r2) {
      float iv = acc[0][r2], fv = acc[1][r2], gv = acc[2][r2], ov = acc[3][r2];
      gv = fminf(fmaxf(gv, -15.f), 15.f);
      float ei = __expf(-iv), ef = __expf(-fv), eg = __expf(2.f * gv);
      float sf = rcpf(1.f + ef);
      float itg = (eg - 1.f) * rcpf((1.f + ei) * (eg + 1.f));
      float cN = sf * c1v[r2] + itg;
      c1v[r2] = cN;
      float cc = fminf(fmaxf(cN, -15.f), 15.f);
      float eo = __expf(-ov), ec = __expf(2.f * cc);
      h1v[r2] = (ec - 1.f) * rcpf((1.f + eo) * (ec + 1.f));
      pool[r2] += h1v[r2];
    }
    h1p.x = packh2f(h1v[0], h1v[1]);
    h1p.y = packh2f(h1v[2], h1v[3]);
    *(uint2*)&hb[c][hoff] = h1p;
    __syncthreads();
  }

  csave[4096 + sid] = c1v;
  hsave[4096 + sid] = h1p;
  psave[sid] = pool;
}

// ---------------------------------------------------------------------------
__global__ __launch_bounds__(128) void final_kernel(
    const f32x4* __restrict__ psave, const float* __restrict__ lin_w,
    const float* __restrict__ lin_b, float* __restrict__ out) {
  int b = threadIdx.x;
  int n = b & 15, b16 = b >> 4;
  float acc = 0.f;
  for (int w = 0; w < 8; ++w)
#pragma unroll
    for (int q = 0; q < 4; ++q) {
      f32x4 v = psave[(b16 * 8 + w) * 64 + n + 16 * q];
#pragma unroll
      for (int reg = 0; reg < 4; ++reg)
        acc += v[reg] * lin_w[w * 16 + q * 4 + reg];
    }
  out[b] = acc * (1.0f / (float)T_) + lin_b[0];
}

// ---------------------------------------------------------------------------
extern "C" void kernel_launch(void* const* d_in, const int* in_sizes, int n_in,
                              void* d_out, int out_size, void* d_ws, size_t ws_size,
                              hipStream_t stream) {
  (void)in_sizes; (void)n_in; (void)out_size;
  const float* x      = (const float*)d_in[0];
  const float* conv_w = (const float*)d_in[1];
  const float* conv_b = (const float*)d_in[2];
  const float* w_ih0  = (const float*)d_in[3];
  const float* w_hh0  = (const float*)d_in[4];
  const float* b_ih0  = (const float*)d_in[5];
  const float* b_hh0  = (const float*)d_in[6];
  const float* w_ih1  = (const float*)d_in[7];
  const float* w_hh1  = (const float*)d_in[8];
  const float* b_ih1  = (const float*)d_in[9];
  const float* b_hh1  = (const float*)d_in[10];
  const float* lin_w  = (const float*)d_in[11];
  const float* lin_b  = (const float*)d_in[12];

  char* ws = (char*)d_ws;
  uint4* Wf0    = (uint4*)(ws + 0);        // 131072
  uint4* Wih1f  = (uint4*)(ws + 131072);   // 131072
  uint4* Whh1f  = (uint4*)(ws + 262144);   // 131072
  uint4* WB0f   = (uint4*)(ws + 393216);   // 131072
  f32x4* b1fD   = (f32x4*)(ws + 524288);   // 32768
  f32x4* csave  = (f32x4*)(ws + 557056);   // 131072 (c0|c1)
  uint2* hsave  = (uint2*)(ws + 688128);   // 65536  (h0|h1)
  f32x4* psave  = (f32x4*)(ws + 753664);   // 65536
  const size_t base = 819200;

  // per-step chunk buffer cost: x0f 131072 + h0g 32768 + z1g 262144
  const size_t perT = 131072 + 32768 + 262144;
  size_t avail = (ws_size > base) ? (ws_size - base) : 0;
  int chunkT = (int)((avail / perT) / 32) * 32;
  if (chunkT > T_) chunkT = T_;
  if (chunkT < 32) chunkT = 32;

  uint4* x0f = (uint4*)(ws + base);
  uint2* h0g = (uint2*)(ws + base + (size_t)chunkT * 131072);
  f32x4* z1g = (f32x4*)(ws + base + (size_t)chunkT * (131072 + 32768));

  hipMemsetAsync(ws + 557056, 0, 262144, stream);  // c/h/pool state
  pack_kernel<<<136, 256, 0, stream>>>(w_ih0, w_hh0, w_ih1, w_hh1, b_ih1, b_hh1,
                                       Wf0, Wih1f, Whh1f, WB0f, b1fD);

  for (int t0 = 0; t0 < T_; t0 += chunkT) {
    int ct = T_ - t0;
    if (ct > chunkT) ct = chunkT;
    conv_proj_kernel<<<dim3(ct / 32, B_), 512, 0, stream>>>(
        x, conv_w, conv_b, b_ih0, b_hh0, WB0f, x0f, t0);
    recur0_kernel<<<8, 512, 0, stream>>>(Wf0, x0f, csave, hsave, h0g, ct);
    proj1_kernel<<<dim3(ct / 8, 8), 512, 0, stream>>>(
        Wih1f, b1fD, (const _Float16*)h0g, z1g, ct);
    recur1_kernel<<<8, 512, 0, stream>>>(Whh1f, z1g, csave, hsave, psave, ct);
  }

  final_kernel<<<1, 128, 0, stream>>>(psave, lin_w, lin_b, (float*)d_out);
}

// Round 4
// 2241.627 us; speedup vs baseline: 3.5465x; 1.8106x over previous
//
#include <hip/hip_runtime.h>
#include <hip/hip_fp16.h>
#include <cstdint>
#include <cstddef>

#define B_ 128
#define T_ 2048
#define C_ 16
#define CO_ 128
#define H_ 128
#define G_ 512
#define WORKERS 176
#define NBLK (16 + WORKERS)

typedef _Float16 half8 __attribute__((ext_vector_type(8)));
typedef float f32x4 __attribute__((ext_vector_type(4)));

__device__ __forceinline__ unsigned packh2f(float a, float b) {
  union { _Float16 h[2]; unsigned u; } x;
  x.h[0] = (_Float16)a; x.h[1] = (_Float16)b;
  return x.u;
}

__device__ __forceinline__ float rcpf(float x) { return __builtin_amdgcn_rcpf(x); }

__device__ __forceinline__ void lstm_cell(const f32x4* acc, f32x4& c, float* h) {
#pragma unroll
  for (int r = 0; r < 4; ++r) {
    float iv = acc[0][r], fv = acc[1][r], gv = acc[2][r], ov = acc[3][r];
    gv = fminf(fmaxf(gv, -15.f), 15.f);
    float ei = __expf(-iv), ef = __expf(-fv), eg = __expf(2.f * gv);
    float sf = rcpf(1.f + ef);
    float itg = (eg - 1.f) * rcpf((1.f + ei) * (eg + 1.f));
    float cN = sf * c[r] + itg;
    c[r] = cN;
    float cc = fminf(fmaxf(cN, -15.f), 15.f);
    float eo = __expf(-ov), ec = __expf(2.f * cc);
    h[r] = (ec - 1.f) * rcpf((1.f + eo) * (ec + 1.f));
  }
}

// ---------------------------------------------------------------------------
// pack_kernel: fragment-ordered weight buffers (same as R3).
// ---------------------------------------------------------------------------
__global__ __launch_bounds__(256) void pack_kernel(
    const float* __restrict__ w_ih0, const float* __restrict__ w_hh0,
    const float* __restrict__ w_ih1, const float* __restrict__ w_hh1,
    const float* __restrict__ b_ih1, const float* __restrict__ b_hh1,
    uint4* __restrict__ Wf0, uint4* __restrict__ Wih1f,
    uint4* __restrict__ Whh1f, uint4* __restrict__ WB0f,
    f32x4* __restrict__ b1fD) {
  int tid = blockIdx.x * 256 + threadIdx.x;
  if (tid < 24576) {
    int u = tid & 8191, L = u & 63, s = (u >> 6) & 3, tl = (u >> 8) & 3, w = u >> 10;
    int which = tid >> 13;
    const float* src = (which == 0) ? w_hh0 : (which == 1) ? w_ih1 : w_hh1;
    uint4* dst = (which == 0) ? Wf0 : (which == 1) ? Wih1f : Whh1f;
    int m = (w + 8 * tl) * 16 + (L & 15);
    int k0 = s * 32 + (L >> 4) * 8;
    const float* p = src + m * 128 + k0;
    uint4 o;
    o.x = packh2f(p[0], p[1]); o.y = packh2f(p[2], p[3]);
    o.z = packh2f(p[4], p[5]); o.w = packh2f(p[6], p[7]);
    dst[u] = o;
  } else if (tid < 32768) {
    int u = tid - 24576, L = u & 63, s = (u >> 6) & 3, nt = u >> 8;
    int g = nt * 16 + (L & 15);
    int k0 = s * 32 + (L >> 4) * 8;
    const float* p = w_ih0 + g * 128 + k0;
    uint4 o;
    o.x = packh2f(p[0], p[1]); o.y = packh2f(p[2], p[3]);
    o.z = packh2f(p[4], p[5]); o.w = packh2f(p[6], p[7]);
    WB0f[u] = o;
  } else if (tid < 34816) {
    int u2 = tid - 32768;
    int tl = u2 & 3, L = (u2 >> 2) & 63, w = u2 >> 8;
    int q = L >> 4;
    f32x4 o;
#pragma unroll
    for (int reg = 0; reg < 4; ++reg) {
      int row = (w + 8 * tl) * 16 + q * 4 + reg;
      o[reg] = b_ih1[row] + b_hh1[row];
    }
    b1fD[u2] = o;
  }
}

// ---------------------------------------------------------------------------
// persist_kernel: producer-consumer pipeline.
//  blocks 0..7   : layer-0 recurrence (one per batch-group of 16)
//  blocks 8..15  : layer-1 recurrence (lagging consumer of h0 stream)
//  blocks 16..   : workers: conv1d+LeakyReLU+w_ih0 projection -> x0 ring
// Flags: xready[tile*8+b16] counts 16 batch-units done; l0_prog[b16] = steps
// of h0 published. x0f is a ring of R=rmask+1 steps with back-pressure.
// ---------------------------------------------------------------------------
__global__ __launch_bounds__(512, 2) void persist_kernel(
    const float* __restrict__ x, const float* __restrict__ conv_w,
    const float* __restrict__ conv_b, const float* __restrict__ b_ih0,
    const float* __restrict__ b_hh0,
    const uint4* __restrict__ Wf0, const uint4* __restrict__ Wih1f,
    const uint4* __restrict__ Whh1f, const uint4* __restrict__ WB0f,
    const f32x4* __restrict__ b1fD,
    uint4* __restrict__ x0f, uint2* __restrict__ h0g,
    f32x4* __restrict__ psave,
    int* __restrict__ xready, int* __restrict__ l0_prog, int rmask) {
  __shared__ __align__(16) union {
    struct { float xs[34 * 16]; _Float16 yh[32 * 136]; _Float16 x0S[32 * 512]; } wk;
    struct { _Float16 h[2][16 * 136]; _Float16 h0[2][16 * 136]; } rc;
  } sm;

  const int bid = blockIdx.x;
  const int tid = threadIdx.x;
  const int w = tid >> 6, L = tid & 63, q = L >> 4, n = L & 15;

  if (bid < 8) {
    // ---------------- layer-0 recurrence ----------------
    const int b16 = bid;
    half8 WA0[4][4];
#pragma unroll
    for (int tl = 0; tl < 4; ++tl)
#pragma unroll
      for (int s = 0; s < 4; ++s)
        WA0[tl][s] = __builtin_bit_cast(half8, Wf0[((w * 4 + tl) * 4 + s) * 64 + L]);

    f32x4 c0v = {0.f, 0.f, 0.f, 0.f};
    const int hoff = n * 136 + w * 16 + q * 4;
    *(uint2*)&sm.rc.h[1][hoff] = make_uint2(0u, 0u);
    __syncthreads();

    const uint4* xp = x0f + (((size_t)b16 * 8 + w) * 64 + L) * 2;
    uint2* hg = h0g + ((b16 * 16 + n) * 32 + w * 4 + q);
    uint4 pa[4], pb[4];

    for (int g = 0; g < 64; ++g) {
      if (tid == 0) {
        while (__hip_atomic_load(&xready[g * 8 + b16], __ATOMIC_ACQUIRE,
                                 __HIP_MEMORY_SCOPE_AGENT) < 16)
          __builtin_amdgcn_s_sleep(2);
        if (g < 63)
          while (__hip_atomic_load(&xready[(g + 1) * 8 + b16], __ATOMIC_ACQUIRE,
                                   __HIP_MEMORY_SCOPE_AGENT) < 16)
            __builtin_amdgcn_s_sleep(2);
      }
      __syncthreads();
      if (g == 0) {
#pragma unroll
        for (int k = 0; k < 4; ++k) {
          pa[k] = xp[(size_t)k * 8192];
          pb[k] = xp[(size_t)k * 8192 + 1];
        }
      }
#pragma unroll 1
      for (int io = 0; io < 8; ++io) {
#pragma unroll
        for (int k = 0; k < 4; ++k) {
          const int t = g * 32 + io * 4 + k;
          const int c = k & 1, p = c ^ 1;
          f32x4 acc[4];
          {
            half8 xlo = __builtin_bit_cast(half8, pa[k]);
            half8 xhi = __builtin_bit_cast(half8, pb[k]);
            acc[0] = (f32x4){(float)xlo[0], (float)xlo[1], (float)xlo[2], (float)xlo[3]};
            acc[1] = (f32x4){(float)xlo[4], (float)xlo[5], (float)xlo[6], (float)xlo[7]};
            acc[2] = (f32x4){(float)xhi[0], (float)xhi[1], (float)xhi[2], (float)xhi[3]};
            acc[3] = (f32x4){(float)xhi[4], (float)xhi[5], (float)xhi[6], (float)xhi[7]};
          }
          half8 B0[4];
#pragma unroll
          for (int s = 0; s < 4; ++s)
            B0[s] = *(const half8*)&sm.rc.h[p][n * 136 + s * 32 + q * 8];
#pragma unroll
          for (int s = 0; s < 4; ++s)
#pragma unroll
            for (int tl = 0; tl < 4; ++tl)
              acc[tl] = __builtin_amdgcn_mfma_f32_16x16x32_f16(WA0[tl][s], B0[s], acc[tl], 0, 0, 0);

          float h0v[4];
          lstm_cell(acc, c0v, h0v);
          uint2 h0p;
          h0p.x = packh2f(h0v[0], h0v[1]);
          h0p.y = packh2f(h0v[2], h0v[3]);
          *(uint2*)&sm.rc.h[c][hoff] = h0p;
          hg[(size_t)t * 4096] = h0p;

          const bool dopub = (io & 1) && (k == 3);
          if (dopub) asm volatile("s_waitcnt vmcnt(0)" ::: "memory");
          __syncthreads();
          if (dopub && tid == 0)
            __hip_atomic_store(&l0_prog[b16], t + 1, __ATOMIC_RELEASE,
                               __HIP_MEMORY_SCOPE_AGENT);
          int tn = t + 4; if (tn > T_ - 1) tn = T_ - 1;
          const size_t so = (size_t)(tn & rmask) * 8192;
          pa[k] = xp[so];
          pb[k] = xp[so + 1];
        }
      }
    }
  } else if (bid < 16) {
    // ---------------- layer-1 recurrence (lagging) ----------------
    const int b16 = bid - 8;
    half8 WI[4][4], WH[4][4];
#pragma unroll
    for (int tl = 0; tl < 4; ++tl)
#pragma unroll
      for (int s = 0; s < 4; ++s) {
        WI[tl][s] = __builtin_bit_cast(half8, Wih1f[((w * 4 + tl) * 4 + s) * 64 + L]);
        WH[tl][s] = __builtin_bit_cast(half8, Whh1f[((w * 4 + tl) * 4 + s) * 64 + L]);
      }
    f32x4 b1v[4];
#pragma unroll
    for (int tl = 0; tl < 4; ++tl) b1v[tl] = b1fD[(w * 64 + L) * 4 + tl];

    f32x4 c1v = {0.f, 0.f, 0.f, 0.f};
    f32x4 pool = {0.f, 0.f, 0.f, 0.f};
    const int hoff = n * 136 + w * 16 + q * 4;
    *(uint2*)&sm.rc.h[1][hoff] = make_uint2(0u, 0u);
    const int n2 = tid >> 5, jq = tid & 31;
    const uint2* hsrc = h0g + ((b16 * 16 + n2) * 32 + jq);
    uint2 hpf[4];

    for (int p0 = 0; p0 < T_; p0 += 8) {
      int tgt = p0 + 12; if (tgt > T_) tgt = T_;
      if (tid == 0)
        while (__hip_atomic_load(&l0_prog[b16], __ATOMIC_ACQUIRE,
                                 __HIP_MEMORY_SCOPE_AGENT) < tgt)
          __builtin_amdgcn_s_sleep(2);
      __syncthreads();
      if (p0 == 0) {
#pragma unroll
        for (int k = 0; k < 4; ++k) hpf[k] = hsrc[(size_t)k * 4096];
      }
#pragma unroll 1
      for (int io = 0; io < 2; ++io) {
#pragma unroll
        for (int k = 0; k < 4; ++k) {
          const int t = p0 + io * 4 + k;
          const int c = k & 1, p = c ^ 1;
          *(uint2*)&sm.rc.h0[c][n2 * 136 + jq * 4] = hpf[k];
          __syncthreads();
          f32x4 acc[4];
#pragma unroll
          for (int tl = 0; tl < 4; ++tl) acc[tl] = b1v[tl];
          half8 BI[4], BH[4];
#pragma unroll
          for (int s = 0; s < 4; ++s) {
            BI[s] = *(const half8*)&sm.rc.h0[c][n * 136 + s * 32 + q * 8];
            BH[s] = *(const half8*)&sm.rc.h[p][n * 136 + s * 32 + q * 8];
          }
#pragma unroll
          for (int s = 0; s < 4; ++s)
#pragma unroll
            for (int tl = 0; tl < 4; ++tl)
              acc[tl] = __builtin_amdgcn_mfma_f32_16x16x32_f16(WI[tl][s], BI[s], acc[tl], 0, 0, 0);
#pragma unroll
          for (int s = 0; s < 4; ++s)
#pragma unroll
            for (int tl = 0; tl < 4; ++tl)
              acc[tl] = __builtin_amdgcn_mfma_f32_16x16x32_f16(WH[tl][s], BH[s], acc[tl], 0, 0, 0);

          float h1v[4];
          lstm_cell(acc, c1v, h1v);
          pool[0] += h1v[0]; pool[1] += h1v[1];
          pool[2] += h1v[2]; pool[3] += h1v[3];
          uint2 h1p;
          h1p.x = packh2f(h1v[0], h1v[1]);
          h1p.y = packh2f(h1v[2], h1v[3]);
          *(uint2*)&sm.rc.h[c][hoff] = h1p;
          int tn = t + 4; if (tn > T_ - 1) tn = T_ - 1;
          hpf[k] = hsrc[(size_t)tn * 4096];
        }
      }
    }
    psave[(b16 * 8 + w) * 64 + L] = pool;
  } else {
    // ---------------- workers: conv + x0 projection into ring ----------------
    const int wi = bid - 16;
    const int co = tid & 127;
    float cw[48];
#pragma unroll
    for (int i = 0; i < 12; ++i) {
      const float4 v = *(const float4*)(conv_w + co * 48 + i * 4);
      cw[i * 4 + 0] = v.x; cw[i * 4 + 1] = v.y;
      cw[i * 4 + 2] = v.z; cw[i * 4 + 3] = v.w;
    }
    const float cb = conv_b[co];
    half8 WB[4][4];
#pragma unroll
    for (int nt4 = 0; nt4 < 4; ++nt4)
#pragma unroll
      for (int s = 0; s < 4; ++s)
        WB[nt4][s] = __builtin_bit_cast(half8, WB0f[((w * 4 + nt4) * 4 + s) * 64 + L]);
    float b0v[4];
#pragma unroll
    for (int nt4 = 0; nt4 < 4; ++nt4) {
      int gg = (w * 4 + nt4) * 16 + n;
      b0v[nt4] = b_ih0[gg] + b_hh0[gg];
    }
    const int R = rmask + 1;

    for (int u = wi; u < 8192; u += WORKERS) {
      const int tile = u >> 7, b = u & 127;
      const int t0c = tile * 32;
      if (t0c + 32 > R) {
        const int need = t0c + 32 - R;
        if (tid == 0)
          while (__hip_atomic_load(&l0_prog[b >> 4], __ATOMIC_RELAXED,
                                   __HIP_MEMORY_SCOPE_AGENT) < need)
            __builtin_amdgcn_s_sleep(8);
      }
      __syncthreads();

      for (int idx = tid; idx < 544; idx += 512) {
        int row = idx >> 4, cc2 = idx & 15;
        int gt = t0c - 1 + row;
        sm.wk.xs[idx] = (gt >= 0 && gt < T_) ? x[((size_t)b * T_ + gt) * C_ + cc2] : 0.f;
      }
      __syncthreads();

#pragma unroll
      for (int pp = 0; pp < 8; ++pp) {
        int r = pp * 4 + (tid >> 7);
        float acc = cb;
#pragma unroll
        for (int c16 = 0; c16 < 16; ++c16)
#pragma unroll
          for (int kk = 0; kk < 3; ++kk)
            acc += sm.wk.xs[(r + kk) * 16 + c16] * cw[c16 * 3 + kk];
        acc = acc >= 0.f ? acc : 0.01f * acc;
        sm.wk.yh[r * 136 + co] = (_Float16)acc;
      }
      __syncthreads();

#pragma unroll
      for (int mt = 0; mt < 2; ++mt) {
        half8 A[4];
#pragma unroll
        for (int s = 0; s < 4; ++s)
          A[s] = *(const half8*)&sm.wk.yh[(mt * 16 + n) * 136 + s * 32 + q * 8];
#pragma unroll
        for (int nt4 = 0; nt4 < 4; ++nt4) {
          f32x4 acc = {b0v[nt4], b0v[nt4], b0v[nt4], b0v[nt4]};
#pragma unroll
          for (int s = 0; s < 4; ++s)
            acc = __builtin_amdgcn_mfma_f32_16x16x32_f16(A[s], WB[nt4][s], acc, 0, 0, 0);
          int tau = w * 4 + nt4;
          int off = (tau & 7) * 64 + (n >> 2) * 16 + (tau >> 3) * 4 + (n & 3);
#pragma unroll
          for (int reg = 0; reg < 4; ++reg)
            sm.wk.x0S[(mt * 16 + q * 4 + reg) * 512 + off] = (_Float16)acc[reg];
        }
      }
      __syncthreads();

      const int bn = b & 15, bb16 = b >> 4;
      const int trb = t0c & rmask;
#pragma unroll
      for (int kk = 0; kk < 2; ++kk) {
        int cc = kk * 512 + tid;
        int r = cc >> 5, wq = cc & 31;
        int w2 = wq >> 2, q2 = wq & 3;
        const uint4* src = (const uint4*)&sm.wk.x0S[r * 512 + wq * 16];
        size_t gidx = ((((size_t)(trb + r) * 8 + bb16) * 8 + w2) * 64 + (bn + 16 * q2)) * 2;
        x0f[gidx] = src[0];
        x0f[gidx + 1] = src[1];
      }
      asm volatile("s_waitcnt vmcnt(0)" ::: "memory");
      __syncthreads();
      if (tid == 0)
        __hip_atomic_fetch_add(&xready[tile * 8 + bb16], 1, __ATOMIC_RELEASE,
                               __HIP_MEMORY_SCOPE_AGENT);
    }
  }
}

// ---------------------------------------------------------------------------
__global__ __launch_bounds__(128) void final_kernel(
    const f32x4* __restrict__ psave, const float* __restrict__ lin_w,
    const float* __restrict__ lin_b, float* __restrict__ out) {
  int b = threadIdx.x;
  int n = b & 15, b16 = b >> 4;
  float acc = 0.f;
  for (int w = 0; w < 8; ++w)
#pragma unroll
    for (int q = 0; q < 4; ++q) {
      f32x4 v = psave[(b16 * 8 + w) * 64 + n + 16 * q];
#pragma unroll
      for (int reg = 0; reg < 4; ++reg)
        acc += v[reg] * lin_w[w * 16 + q * 4 + reg];
    }
  out[b] = acc * (1.0f / (float)T_) + lin_b[0];
}

// ---------------------------------------------------------------------------
extern "C" void kernel_launch(void* const* d_in, const int* in_sizes, int n_in,
                              void* d_out, int out_size, void* d_ws, size_t ws_size,
                              hipStream_t stream) {
  (void)in_sizes; (void)n_in; (void)out_size;
  const float* x      = (const float*)d_in[0];
  const float* conv_w = (const float*)d_in[1];
  const float* conv_b = (const float*)d_in[2];
  const float* w_ih0  = (const float*)d_in[3];
  const float* w_hh0  = (const float*)d_in[4];
  const float* b_ih0  = (const float*)d_in[5];
  const float* b_hh0  = (const float*)d_in[6];
  const float* w_ih1  = (const float*)d_in[7];
  const float* w_hh1  = (const float*)d_in[8];
  const float* b_ih1  = (const float*)d_in[9];
  const float* b_hh1  = (const float*)d_in[10];
  const float* lin_w  = (const float*)d_in[11];
  const float* lin_b  = (const float*)d_in[12];

  char* ws = (char*)d_ws;
  uint4* Wf0   = (uint4*)(ws + 0);        // 131072
  uint4* Wih1f = (uint4*)(ws + 131072);   // 131072
  uint4* Whh1f = (uint4*)(ws + 262144);   // 131072
  uint4* WB0f  = (uint4*)(ws + 393216);   // 131072
  f32x4* b1fD  = (f32x4*)(ws + 524288);   // 32768
  f32x4* psave = (f32x4*)(ws + 557056);   // 65536
  int*   flags = (int*)(ws + 622592);     // 4096: xready[512] | l0_prog[8]
  uint2* h0g   = (uint2*)(ws + 626688);   // 67108864 (full-T h0 stream)
  uint4* x0f   = (uint4*)(ws + 626688 + 67108864);  // ring, R*131072

  size_t avail = (ws_size > 67735552) ? (ws_size - 67735552) : 0;
  int R = 512;
  while (R > 64 && (size_t)R * 131072 > avail) R >>= 1;

  hipMemsetAsync(flags, 0, 4096, stream);
  pack_kernel<<<136, 256, 0, stream>>>(w_ih0, w_hh0, w_ih1, w_hh1, b_ih1, b_hh1,
                                       Wf0, Wih1f, Whh1f, WB0f, b1fD);
  persist_kernel<<<NBLK, 512, 0, stream>>>(
      x, conv_w, conv_b, b_ih0, b_hh0, Wf0, Wih1f, Whh1f, WB0f, b1fD,
      x0f, h0g, psave, flags, flags + 512, R - 1);
  final_kernel<<<1, 128, 0, stream>>>(psave, lin_w, lin_b, (float*)d_out);
}